// Round 3
// baseline (1357.120 us; speedup 1.0000x reference)
//
#include <hip/hip_runtime.h>
#include <cmath>

constexpr int BN = 16, CN = 64, HN = 256, WN = 256;
constexpr int IMG = HN * WN;
constexpr float EPSF = 0.001f;

typedef short bf16x8 __attribute__((ext_vector_type(8)));
typedef float f32x4  __attribute__((ext_vector_type(4)));

// ---- bf16 helpers (RNE, finite inputs) ------------------------------------
__device__ __forceinline__ unsigned short f2bf(float f) {
    unsigned u = __builtin_bit_cast(unsigned, f);
    u += 0x7fffu + ((u >> 16) & 1u);
    return (unsigned short)(u >> 16);
}
__device__ __forceinline__ float bf2f(unsigned short h) {
    return __builtin_bit_cast(float, ((unsigned)h) << 16);
}

__device__ __forceinline__ void gload16(const void* g, void* l) {
    __builtin_amdgcn_global_load_lds(
        (const __attribute__((address_space(1))) unsigned int*)g,
        (__attribute__((address_space(3))) unsigned int*)l, 16, 0, 0);
}

// ---------------------------------------------------------------------------
// Weight prep: W[co][ci][3][3] fp32 -> bf16 MFMA A-fragments
// wprep[(ct*9+s)*2+kk][lane][e]  with co=ct*16+(lane&15), ci=kk*32+(lane>>4)*8+e
// ---------------------------------------------------------------------------
__global__ __launch_bounds__(256)
void k_wprep(const float* __restrict__ w, unsigned short* __restrict__ wp) {
    int flat = blockIdx.x * 256 + threadIdx.x;       // 0..36863
    int ct = flat / 9216;
    int r1 = flat % 9216;
    int s  = r1 / 1024;
    int r2 = r1 % 1024;
    int kk = r2 >> 9;
    int l  = (r2 >> 3) & 63;
    int e  = r2 & 7;
    int co = ct * 16 + (l & 15);
    int ci = kk * 32 + (l >> 4) * 8 + e;
    int kh = s / 3, kw = s % 3;
    wp[flat] = f2bf(w[((co * 64 + ci) * 3 + kh) * 3 + kw]);
}

// ---------------------------------------------------------------------------
// Pass 1: x[b][c][i][j] fp32 -> lpT[b][i][j][c] bf16   (coords shared over c)
// ---------------------------------------------------------------------------
__global__ __launch_bounds__(256)
void k_c2lp(const float* __restrict__ x, unsigned short* __restrict__ lpT,
            float lr_scale, float th_scale) {
    __shared__ alignas(16) unsigned char sm[WN * CN * 2];   // 32 KB [j][c] bf16
    const int j = threadIdx.x;
    const int i = blockIdx.x;
    const int b = blockIdx.y;

    float r  = __expf((float)j * lr_scale);
    float th = (float)i * th_scale;
    float gx = fmaf(r, cosf(th), 127.5f);
    float gy = fmaf(r, sinf(th), 127.5f);

    float left = floorf(gx), top = floorf(gy);
    int li = (int)left, ti = (int)top, ri = li + 1, bi = ti + 1;
    float dl = gx - left, dr = left + 1.0f - gx;
    float dt = gy - top,  db = top + 1.0f - gy;
    float wtl = db * dr, wtr = db * dl, wbl = dt * dr, wbr = dt * dl;

    bool vl = (li >= 0 && li < WN), vr = (ri >= 0 && ri < WN);
    bool vt = (ti >= 0 && ti < HN), vb = (bi >= 0 && bi < HN);
    bool v_tl = vl && vt, v_tr = vr && vt, v_bl = vl && vb, v_br = vr && vb;
    int o_tl = ti * WN + li, o_tr = ti * WN + ri;
    int o_bl = bi * WN + li, o_br = bi * WN + ri;

    const float* xb = x + (size_t)b * CN * IMG;
#pragma unroll 2
    for (int c0 = 0; c0 < CN; c0 += 8) {
        unsigned short p[8];
#pragma unroll
        for (int e = 0; e < 8; ++e) {
            const float* img = xb + (size_t)(c0 + e) * IMG;
            float tl = v_tl ? img[o_tl] : 0.0f;
            float tr = v_tr ? img[o_tr] : 0.0f;
            float bl = v_bl ? img[o_bl] : 0.0f;
            float br = v_br ? img[o_br] : 0.0f;
            p[e] = f2bf(wtl * tl + wtr * tr + wbl * bl + wbr * br);
        }
        int byte = (j << 7) + (c0 << 1);
        byte ^= (j & 7) << 4;                 // bank swizzle
        *(uint4*)(sm + byte) = *(const uint4*)p;
    }
    __syncthreads();
    // coalesced readout: 2048 x 16B units, linear in global
    char* dst = (char*)lpT + (size_t)(b * HN + i) * (WN * CN * 2);
#pragma unroll
    for (int k = 0; k < 8; ++k) {
        int u = k * 256 + threadIdx.x;
        int jj = u >> 3, ch = u & 7;
        int byte = (jj << 7) + (((ch ^ (jj & 7))) << 4);
        *(uint4*)(dst + (size_t)u * 16) = *(const uint4*)(sm + byte);
    }
}

// ---------------------------------------------------------------------------
// Pass 2: MFMA conv. block = (b, i, j0..j0+127) x 64 co, 4 waves.
// LDS stage [3][130][64] bf16 (49920 B), XOR-swizzled 16B chunks.
// ---------------------------------------------------------------------------
__global__ __launch_bounds__(256)
void k_conv(const unsigned short* __restrict__ lpT,
            const unsigned short* __restrict__ wp,
            const float* __restrict__ bias,
            unsigned short* __restrict__ yT) {
    __shared__ alignas(16) unsigned char sm[3 * 130 * 64 * 2];   // 49920 B
    const int tid = threadIdx.x;
    const int w = tid >> 6, lane = tid & 63;
    const int lanelo = lane & 15, lanehi = lane >> 4;
    const int j0 = blockIdx.x * 128;
    const int i  = blockIdx.y;
    const int b  = blockIdx.z;

    // ---- stage 3 rows x 130 cols x 64 ci (3120 16B units) ----
    for (int u0 = 0; u0 < 3120; u0 += 256) {
        int unit = u0 + tid;
        if (unit < 3120) {
            int r   = unit / 1040;
            int rem = unit - r * 1040;
            int col = rem >> 3, ch = rem & 7;
            int ii = i - 1 + r;
            int jj = j0 - 1 + col;
            void* lptr = sm + unit * 16;
            if ((unsigned)ii < 256u && (unsigned)jj < 256u) {
                int sch = ch ^ (col & 7);        // pre-swizzled source
                const unsigned short* g =
                    lpT + (((size_t)(b * 256 + ii) * 256 + jj) * 64 + sch * 8);
                gload16(g, lptr);
            } else {
                uint4 z; z.x = z.y = z.z = z.w = 0;
                *(uint4*)lptr = z;
            }
        }
    }

    // ---- weights: 18 A-fragments for this wave's 16 co ----
    bf16x8 af[18];
#pragma unroll
    for (int sk = 0; sk < 18; ++sk)
        af[sk] = *(const bf16x8*)(wp + ((size_t)(w * 18 + sk) * 64 + lane) * 8);

    // ---- accumulators init with bias (C/D row = co = lanehi*4 + reg) ----
    int co_row = w * 16 + lanehi * 4;
    f32x4 binit = { bias[co_row], bias[co_row + 1], bias[co_row + 2], bias[co_row + 3] };
    f32x4 acc[8];
#pragma unroll
    for (int n = 0; n < 8; ++n) acc[n] = binit;

    __syncthreads();

    // ---- 9 shifts x 2 K-steps x 8 col-fragments ----
#pragma unroll
    for (int s = 0; s < 9; ++s) {
        const int kh = s / 3, kw = s % 3;
#pragma unroll
        for (int kk = 0; kk < 2; ++kk) {
            const int cih = kk * 4 + lanehi;        // ci>>3
#pragma unroll
            for (int n = 0; n < 8; ++n) {
                int col  = n * 16 + lanelo + kw;    // 0..129
                int unit = (kh * 130 + col) * 8 + (cih ^ (col & 7));
                bf16x8 bf = *(const bf16x8*)(sm + unit * 16);
                acc[n] = __builtin_amdgcn_mfma_f32_16x16x32_bf16(
                    af[s * 2 + kk], bf, acc[n], 0, 0, 0);
            }
        }
    }

    __syncthreads();    // all ds_reads done; reuse sm for out tile [128][64] bf16

#pragma unroll
    for (int n = 0; n < 8; ++n) {
        int col = n * 16 + lanelo;
        int co  = w * 16 + lanehi * 4;
        unsigned short p[4];
#pragma unroll
        for (int r = 0; r < 4; ++r) p[r] = f2bf(acc[n][r]);
        int byte = (col << 7) + (co << 1);
        byte ^= (col & 7) << 4;
        *(uint2*)(sm + byte) = *(const uint2*)p;
    }
    __syncthreads();

    char* dst = (char*)yT + ((size_t)(b * 256 + i) * 256 + j0) * 128;  // *64ch*2B
#pragma unroll
    for (int k = 0; k < 4; ++k) {
        int u = k * 256 + tid;                     // 1024 units of 16B
        int col = u >> 3, ch = u & 7;
        int byte = (col << 7) + ((ch ^ (col & 7)) << 4);
        *(uint4*)(dst + (size_t)u * 16) = *(const uint4*)(sm + byte);
    }
}

// ---------------------------------------------------------------------------
// Pass 3: yT[b][i][j][c] bf16 -> out[b][c][i][j] fp32
// One c-group (8 channels) per thread; blockIdx.z selects the group.
// Non-temporal stores keep the 256 MB out-stream from evicting yT from L3.
// ---------------------------------------------------------------------------
__global__ __launch_bounds__(256)
void k_lp2c(const unsigned short* __restrict__ yT, float* __restrict__ out,
            float gx_scale, float gy_scale) {
    const int j  = threadIdx.x;
    const int i  = blockIdx.x;
    const int b  = blockIdx.y;
    const int c0 = blockIdx.z * 8;

    float X = (float)j - 127.5f;
    float Y = (float)i - 127.5f;
    float R = sqrtf(X * X + Y * Y);
    float Th = atan2f(Y, X + EPSF);
    if (Th < 0.0f) Th += 6.2831853071795864769f;
    float gx = logf(R + EPSF) * gx_scale;
    float gy = Th * gy_scale;

    float left = floorf(gx), top = floorf(gy);
    int li = (int)left, ti = (int)top, ri = li + 1, bi = ti + 1;
    float dl = gx - left, dr = left + 1.0f - gx;
    float dt = gy - top,  db = top + 1.0f - gy;
    float wtl = db * dr, wtr = db * dl, wbl = dt * dr, wbr = dt * dl;

    bool vl = (li >= 0 && li < WN), vr = (ri >= 0 && ri < WN);
    bool vt = (ti >= 0 && ti < HN), vb = (bi >= 0 && bi < HN);
    bool v_tl = vl && vt, v_tr = vr && vt, v_bl = vl && vb, v_br = vr && vb;

    const unsigned short* yb = yT + (size_t)b * IMG * CN + c0;
    size_t o_tl = ((size_t)ti * WN + li) * CN, o_tr = ((size_t)ti * WN + ri) * CN;
    size_t o_bl = ((size_t)bi * WN + li) * CN, o_br = ((size_t)bi * WN + ri) * CN;

    union U8 { uint4 u; unsigned short s[8]; };
    uint4 z; z.x = z.y = z.z = z.w = 0;
    U8 tl, tr, bl, br;
    tl.u = v_tl ? *(const uint4*)(yb + o_tl) : z;
    tr.u = v_tr ? *(const uint4*)(yb + o_tr) : z;
    bl.u = v_bl ? *(const uint4*)(yb + o_bl) : z;
    br.u = v_br ? *(const uint4*)(yb + o_br) : z;

    float* ob = out + ((size_t)(b * CN + c0)) * IMG + i * WN + j;
#pragma unroll
    for (int e = 0; e < 8; ++e) {
        float v = wtl * bf2f(tl.s[e]) + wtr * bf2f(tr.s[e])
                + wbl * bf2f(bl.s[e]) + wbr * bf2f(br.s[e]);
        __builtin_nontemporal_store(v, ob + (size_t)e * IMG);
    }
}

// ---------------------------------------------------------------------------
extern "C" void kernel_launch(void* const* d_in, const int* in_sizes, int n_in,
                              void* d_out, int out_size, void* d_ws, size_t ws_size,
                              hipStream_t stream) {
    const float* x    = (const float*)d_in[0];
    const float* wgt  = (const float*)d_in[1];
    const float* bias = (const float*)d_in[2];

    // log-polar params (double precision on host, truncated to f32)
    const double cx = (WN - 1) / 2.0;
    const double xm = WN - cx;                    // 128.5
    const double rmax = sqrt(2.0 * xm * xm);
    const double lrm = log(rmax + 0.001);
    const float lr_scale = (float)(lrm / WN);
    const float th_scale = (float)(2.0 * M_PI / HN);
    const float gx_scale = (float)(WN / lrm);
    const float gy_scale = (float)(HN / (2.0 * M_PI));

    const size_t half = (size_t)BN * HN * WN * CN * 2;       // 128 MB bf16
    unsigned short* lpT = (unsigned short*)d_ws;
    unsigned short* yT  = (unsigned short*)((char*)d_ws + half);
    unsigned short* wp  = (unsigned short*)d_out;            // scratch until pass 3

    dim3 blk(256, 1, 1);

    k_wprep<<<dim3(144, 1, 1), blk, 0, stream>>>(wgt, wp);
    k_c2lp <<<dim3(HN, BN, 1), blk, 0, stream>>>(x, lpT, lr_scale, th_scale);
    k_conv <<<dim3(WN / 128, HN, BN), blk, 0, stream>>>(lpT, wp, bias, yT);
    k_lp2c <<<dim3(HN, BN, 8), blk, 0, stream>>>(yT, (float*)d_out, gx_scale, gy_scale);
}

// Round 4
// 1086.802 us; speedup vs baseline: 1.2487x; 1.2487x over previous
//
#include <hip/hip_runtime.h>
#include <cmath>

constexpr int BN = 16, CN = 64, HN = 256, WN = 256;
constexpr int IMG = HN * WN;
constexpr float EPSF = 0.001f;

typedef short bf16x8 __attribute__((ext_vector_type(8)));
typedef float f32x4  __attribute__((ext_vector_type(4)));

// ---- bf16 helpers (RNE, finite inputs) ------------------------------------
__device__ __forceinline__ unsigned short f2bf(float f) {
    unsigned u = __builtin_bit_cast(unsigned, f);
    u += 0x7fffu + ((u >> 16) & 1u);
    return (unsigned short)(u >> 16);
}
__device__ __forceinline__ float bf2f(unsigned short h) {
    return __builtin_bit_cast(float, ((unsigned)h) << 16);
}

__device__ __forceinline__ void gload16(const void* g, void* l) {
    __builtin_amdgcn_global_load_lds(
        (const __attribute__((address_space(1))) unsigned int*)g,
        (__attribute__((address_space(3))) unsigned int*)l, 16, 0, 0);
}

// ---------------------------------------------------------------------------
// Weight prep: W[co][ci][3][3] fp32 -> bf16 MFMA A-fragments
// wprep[(ct*9+s)*2+kk][lane][e]  with co=ct*16+(lane&15), ci=kk*32+(lane>>4)*8+e
// ---------------------------------------------------------------------------
__global__ __launch_bounds__(256)
void k_wprep(const float* __restrict__ w, unsigned short* __restrict__ wp) {
    int flat = blockIdx.x * 256 + threadIdx.x;       // 0..36863
    int ct = flat / 9216;
    int r1 = flat % 9216;
    int s  = r1 / 1024;
    int r2 = r1 % 1024;
    int kk = r2 >> 9;
    int l  = (r2 >> 3) & 63;
    int e  = r2 & 7;
    int co = ct * 16 + (l & 15);
    int ci = kk * 32 + (l >> 4) * 8 + e;
    int kh = s / 3, kw = s % 3;
    wp[flat] = f2bf(w[((co * 64 + ci) * 3 + kh) * 3 + kw]);
}

// ---------------------------------------------------------------------------
// Pass 1: x[b][c][i][j] fp32 -> lpT[b][i][j][c] bf16   (coords shared over c)
// ---------------------------------------------------------------------------
__global__ __launch_bounds__(256)
void k_c2lp(const float* __restrict__ x, unsigned short* __restrict__ lpT,
            float lr_scale, float th_scale) {
    __shared__ alignas(16) unsigned char sm[WN * CN * 2];   // 32 KB [j][c] bf16
    const int j = threadIdx.x;
    const int i = blockIdx.x;
    const int b = blockIdx.y;

    float r  = __expf((float)j * lr_scale);
    float th = (float)i * th_scale;
    float gx = fmaf(r, cosf(th), 127.5f);
    float gy = fmaf(r, sinf(th), 127.5f);

    float left = floorf(gx), top = floorf(gy);
    int li = (int)left, ti = (int)top, ri = li + 1, bi = ti + 1;
    float dl = gx - left, dr = left + 1.0f - gx;
    float dt = gy - top,  db = top + 1.0f - gy;
    float wtl = db * dr, wtr = db * dl, wbl = dt * dr, wbr = dt * dl;

    bool vl = (li >= 0 && li < WN), vr = (ri >= 0 && ri < WN);
    bool vt = (ti >= 0 && ti < HN), vb = (bi >= 0 && bi < HN);
    bool v_tl = vl && vt, v_tr = vr && vt, v_bl = vl && vb, v_br = vr && vb;
    int o_tl = ti * WN + li, o_tr = ti * WN + ri;
    int o_bl = bi * WN + li, o_br = bi * WN + ri;

    const float* xb = x + (size_t)b * CN * IMG;
#pragma unroll 2
    for (int c0 = 0; c0 < CN; c0 += 8) {
        unsigned short p[8];
#pragma unroll
        for (int e = 0; e < 8; ++e) {
            const float* img = xb + (size_t)(c0 + e) * IMG;
            float tl = v_tl ? img[o_tl] : 0.0f;
            float tr = v_tr ? img[o_tr] : 0.0f;
            float bl = v_bl ? img[o_bl] : 0.0f;
            float br = v_br ? img[o_br] : 0.0f;
            p[e] = f2bf(wtl * tl + wtr * tr + wbl * bl + wbr * br);
        }
        int byte = (j << 7) + (c0 << 1);
        byte ^= (j & 7) << 4;                 // bank swizzle
        *(uint4*)(sm + byte) = *(const uint4*)p;
    }
    __syncthreads();
    // coalesced readout: 2048 x 16B units, linear in global
    char* dst = (char*)lpT + (size_t)(b * HN + i) * (WN * CN * 2);
#pragma unroll
    for (int k = 0; k < 8; ++k) {
        int u = k * 256 + threadIdx.x;
        int jj = u >> 3, ch = u & 7;
        int byte = (jj << 7) + (((ch ^ (jj & 7))) << 4);
        *(uint4*)(dst + (size_t)u * 16) = *(const uint4*)(sm + byte);
    }
}

// ---------------------------------------------------------------------------
// Pass 2: MFMA conv. block = (b, i, j0..j0+127) x 64 co, 4 waves.
// LDS stage [3][130][64] bf16 (49920 B), XOR-swizzled 16B chunks.
// ---------------------------------------------------------------------------
__global__ __launch_bounds__(256)
void k_conv(const unsigned short* __restrict__ lpT,
            const unsigned short* __restrict__ wp,
            const float* __restrict__ bias,
            unsigned short* __restrict__ yT) {
    __shared__ alignas(16) unsigned char sm[3 * 130 * 64 * 2];   // 49920 B
    const int tid = threadIdx.x;
    const int w = tid >> 6, lane = tid & 63;
    const int lanelo = lane & 15, lanehi = lane >> 4;
    const int j0 = blockIdx.x * 128;
    const int i  = blockIdx.y;
    const int b  = blockIdx.z;

    // ---- stage 3 rows x 130 cols x 64 ci (3120 16B units) ----
    for (int u0 = 0; u0 < 3120; u0 += 256) {
        int unit = u0 + tid;
        if (unit < 3120) {
            int r   = unit / 1040;
            int rem = unit - r * 1040;
            int col = rem >> 3, ch = rem & 7;
            int ii = i - 1 + r;
            int jj = j0 - 1 + col;
            void* lptr = sm + unit * 16;
            if ((unsigned)ii < 256u && (unsigned)jj < 256u) {
                int sch = ch ^ (col & 7);        // pre-swizzled source
                const unsigned short* g =
                    lpT + (((size_t)(b * 256 + ii) * 256 + jj) * 64 + sch * 8);
                gload16(g, lptr);
            } else {
                uint4 z; z.x = z.y = z.z = z.w = 0;
                *(uint4*)lptr = z;
            }
        }
    }

    // ---- weights: 18 A-fragments for this wave's 16 co ----
    bf16x8 af[18];
#pragma unroll
    for (int sk = 0; sk < 18; ++sk)
        af[sk] = *(const bf16x8*)(wp + ((size_t)(w * 18 + sk) * 64 + lane) * 8);

    // ---- accumulators init with bias (C/D row = co = lanehi*4 + reg) ----
    int co_row = w * 16 + lanehi * 4;
    f32x4 binit = { bias[co_row], bias[co_row + 1], bias[co_row + 2], bias[co_row + 3] };
    f32x4 acc[8];
#pragma unroll
    for (int n = 0; n < 8; ++n) acc[n] = binit;

    __syncthreads();

    // ---- 9 shifts x 2 K-steps x 8 col-fragments ----
#pragma unroll
    for (int s = 0; s < 9; ++s) {
        const int kh = s / 3, kw = s % 3;
#pragma unroll
        for (int kk = 0; kk < 2; ++kk) {
            const int cih = kk * 4 + lanehi;        // ci>>3
#pragma unroll
            for (int n = 0; n < 8; ++n) {
                int col  = n * 16 + lanelo + kw;    // 0..129
                int unit = (kh * 130 + col) * 8 + (cih ^ (col & 7));
                bf16x8 bf = *(const bf16x8*)(sm + unit * 16);
                acc[n] = __builtin_amdgcn_mfma_f32_16x16x32_bf16(
                    af[s * 2 + kk], bf, acc[n], 0, 0, 0);
            }
        }
    }

    __syncthreads();    // all ds_reads done; reuse sm for out tile [128][64] bf16

#pragma unroll
    for (int n = 0; n < 8; ++n) {
        int col = n * 16 + lanelo;
        int co  = w * 16 + lanehi * 4;
        unsigned short p[4];
#pragma unroll
        for (int r = 0; r < 4; ++r) p[r] = f2bf(acc[n][r]);
        int byte = (col << 7) + (co << 1);
        byte ^= (col & 7) << 4;
        *(uint2*)(sm + byte) = *(const uint2*)p;
    }
    __syncthreads();

    char* dst = (char*)yT + ((size_t)(b * 256 + i) * 256 + j0) * 128;  // *64ch*2B
#pragma unroll
    for (int k = 0; k < 4; ++k) {
        int u = k * 256 + tid;                     // 1024 units of 16B
        int col = u >> 3, ch = u & 7;
        int byte = (col << 7) + ((ch ^ (col & 7)) << 4);
        *(uint4*)(dst + (size_t)u * 16) = *(const uint4*)(sm + byte);
    }
}

// ---------------------------------------------------------------------------
// Pass 3: yT[b][i][j][c] bf16 -> out[b][c][i][j] fp32.
// Block = 64 j-positions x 4 channel-quarters (SAME block shares the 128B
// corner lines -> no redundant HBM fetch). Each thread: 16 channels,
// 8 independent 16B loads -> one vmcnt wait -> 16 coalesced nt stores.
// ---------------------------------------------------------------------------
__global__ __launch_bounds__(256)
void k_lp2c(const unsigned short* __restrict__ yT, float* __restrict__ out,
            float gx_scale, float gy_scale) {
    const int tid = threadIdx.x;
    const int q   = tid >> 6;              // channel quarter 0..3
    const int jl  = tid & 63;
    const int j   = blockIdx.x * 64 + jl;
    const int i   = blockIdx.y;
    const int b   = blockIdx.z;
    const int c0  = q * 16;

    float X = (float)j - 127.5f;
    float Y = (float)i - 127.5f;
    float R = sqrtf(X * X + Y * Y);
    float Th = atan2f(Y, X + EPSF);
    if (Th < 0.0f) Th += 6.2831853071795864769f;
    float gx = logf(R + EPSF) * gx_scale;
    float gy = Th * gy_scale;

    float left = floorf(gx), top = floorf(gy);
    int li = (int)left, ti = (int)top, ri = li + 1, bi = ti + 1;
    float dl = gx - left, dr = left + 1.0f - gx;
    float dt = gy - top,  db = top + 1.0f - gy;
    float wtl = db * dr, wtr = db * dl, wbl = dt * dr, wbr = dt * dl;

    bool vl = (li >= 0 && li < WN), vr = (ri >= 0 && ri < WN);
    bool vt = (ti >= 0 && ti < HN), vb = (bi >= 0 && bi < HN);
    bool v_tl = vl && vt, v_tr = vr && vt, v_bl = vl && vb, v_br = vr && vb;

    const unsigned short* yb = yT + (size_t)b * IMG * CN + c0;
    size_t o_tl = ((size_t)ti * WN + li) * CN, o_tr = ((size_t)ti * WN + ri) * CN;
    size_t o_bl = ((size_t)bi * WN + li) * CN, o_br = ((size_t)bi * WN + ri) * CN;

    union U16 { uint4 u[2]; unsigned short s[16]; };
    uint4 z; z.x = z.y = z.z = z.w = 0;
    U16 tl, tr, bl, br;
    // 8 independent 16B loads (vl/vr etc. predicated)
    tl.u[0] = v_tl ? *(const uint4*)(yb + o_tl)     : z;
    tl.u[1] = v_tl ? *(const uint4*)(yb + o_tl + 8) : z;
    tr.u[0] = v_tr ? *(const uint4*)(yb + o_tr)     : z;
    tr.u[1] = v_tr ? *(const uint4*)(yb + o_tr + 8) : z;
    bl.u[0] = v_bl ? *(const uint4*)(yb + o_bl)     : z;
    bl.u[1] = v_bl ? *(const uint4*)(yb + o_bl + 8) : z;
    br.u[0] = v_br ? *(const uint4*)(yb + o_br)     : z;
    br.u[1] = v_br ? *(const uint4*)(yb + o_br + 8) : z;

    float* ob = out + ((size_t)(b * CN + c0)) * IMG + i * WN + j;
#pragma unroll
    for (int e = 0; e < 16; ++e) {
        float v = wtl * bf2f(tl.s[e]) + wtr * bf2f(tr.s[e])
                + wbl * bf2f(bl.s[e]) + wbr * bf2f(br.s[e]);
        __builtin_nontemporal_store(v, ob + (size_t)e * IMG);
    }
}

// ---------------------------------------------------------------------------
extern "C" void kernel_launch(void* const* d_in, const int* in_sizes, int n_in,
                              void* d_out, int out_size, void* d_ws, size_t ws_size,
                              hipStream_t stream) {
    const float* x    = (const float*)d_in[0];
    const float* wgt  = (const float*)d_in[1];
    const float* bias = (const float*)d_in[2];

    // log-polar params (double precision on host, truncated to f32)
    const double cx = (WN - 1) / 2.0;
    const double xm = WN - cx;                    // 128.5
    const double rmax = sqrt(2.0 * xm * xm);
    const double lrm = log(rmax + 0.001);
    const float lr_scale = (float)(lrm / WN);
    const float th_scale = (float)(2.0 * M_PI / HN);
    const float gx_scale = (float)(WN / lrm);
    const float gy_scale = (float)(HN / (2.0 * M_PI));

    const size_t half = (size_t)BN * HN * WN * CN * 2;       // 128 MB bf16
    unsigned short* lpT = (unsigned short*)d_ws;
    unsigned short* yT  = (unsigned short*)((char*)d_ws + half);
    unsigned short* wp  = (unsigned short*)d_out;            // scratch until pass 3

    dim3 blk(256, 1, 1);

    k_wprep<<<dim3(144, 1, 1), blk, 0, stream>>>(wgt, wp);
    k_c2lp <<<dim3(HN, BN, 1), blk, 0, stream>>>(x, lpT, lr_scale, th_scale);
    k_conv <<<dim3(WN / 128, HN, BN), blk, 0, stream>>>(lpT, wp, bias, yT);
    k_lp2c <<<dim3(WN / 64, HN, BN), blk, 0, stream>>>(yT, (float*)d_out, gx_scale, gy_scale);
}